// Round 5
// baseline (633.730 us; speedup 1.0000x reference)
//
#include <hip/hip_runtime.h>

#define BB 4
#define CC 84
#define CM 80
#define HH 512
#define WW 512
#define HWSZ (HH * WW)
#define PG (HWSZ / 4)          // 65536 float4 pixel-groups per image
#define NCH 4
#define CPC (CM / NCH)         // 20 channels per chunk

typedef float v4f __attribute__((ext_vector_type(4)));

static __device__ __forceinline__ v4f vmax4(v4f a, v4f b) {
    v4f r;
    r.x = fmaxf(a.x, b.x);
    r.y = fmaxf(a.y, b.y);
    r.z = fmaxf(a.z, b.z);
    r.w = fmaxf(a.w, b.w);
    return r;
}

// ---------------- K1: partial channel-max, 4 independent load/acc chains ----
// partial layout: [(chunk*BB + b)*PG + pg] float4
__global__ __launch_bounds__(256) void partial_max_kernel(const float* __restrict__ pts,
                                                          float* __restrict__ partial) {
    int tid = blockIdx.x * blockDim.x + threadIdx.x;   // BB*NCH*PG threads
    int pg  = tid & (PG - 1);
    int r   = tid >> 16;
    int chunk = r % NCH;
    int b     = r / NCH;

    const v4f* base = (const v4f*)pts + ((size_t)b * CC + chunk * CPC) * PG + pg;

    // 4 independent accumulator chains; loads grouped so 4+ are always in flight
    v4f a0 = base[0 * PG];
    v4f a1 = base[1 * PG];
    v4f a2 = base[2 * PG];
    v4f a3 = base[3 * PG];
#pragma unroll
    for (int c = 4; c < CPC; c += 4) {
        v4f w0 = base[(size_t)(c + 0) * PG];
        v4f w1 = base[(size_t)(c + 1) * PG];
        v4f w2 = base[(size_t)(c + 2) * PG];
        v4f w3 = base[(size_t)(c + 3) * PG];
        a0 = vmax4(a0, w0);
        a1 = vmax4(a1, w1);
        a2 = vmax4(a2, w2);
        a3 = vmax4(a3, w3);
    }
    v4f m = vmax4(vmax4(a0, a1), vmax4(a2, a3));
    ((v4f*)partial)[((size_t)chunk * BB + b) * PG + pg] = m;
}

// ---------------- K2: fused combine + 3x3 NMS mask --------------------------
// probs(b,h,w) = max over 4 partial planes; mask per reference:
// raster idx < center uses strict >, idx > center uses >=; zero padding.
__global__ __launch_bounds__(256) void fused_mask_kernel(const float* __restrict__ partial,
                                                         float* __restrict__ mask) {
    int tid = blockIdx.x * blockDim.x + threadIdx.x;   // BB*PG threads
    int pg  = tid & (PG - 1);
    int b   = tid >> 16;
    int off = pg << 2;
    int h   = off >> 9;
    int w0  = off & (WW - 1);

    float rows[3][6];
#pragma unroll
    for (int r = 0; r < 3; ++r) {
        int hh = h + r - 1;
        bool hv = (hh >= 0) & (hh < HH);
#pragma unroll
        for (int ci = 0; ci < 6; ++ci) {
            int ww = w0 + ci - 1;
            bool wv = (ww >= 0) & (ww < WW);
            float v = 0.0f;
            if (hv & wv) {
                int pidx = hh * WW + ww;
                v = partial[(size_t)(0 * BB + b) * HWSZ + pidx];
#pragma unroll
                for (int ch = 1; ch < NCH; ++ch)
                    v = fmaxf(v, partial[(size_t)(ch * BB + b) * HWSZ + pidx]);
            }
            rows[r][ci] = v;
        }
    }

    v4f fm;
#pragma unroll
    for (int j = 0; j < 4; ++j) {
        float v = rows[1][j + 1];
        bool m = (v >  rows[0][j]) & (v >  rows[0][j + 1]) & (v >  rows[0][j + 2])
               & (v >  rows[1][j]) & (v >= rows[1][j + 2])
               & (v >= rows[2][j]) & (v >= rows[2][j + 1]) & (v >= rows[2][j + 2]);
        float f = m ? 1.0f : 0.0f;
        if (j == 0) fm.x = f;
        else if (j == 1) fm.y = f;
        else if (j == 2) fm.z = f;
        else fm.w = f;
    }
    ((v4f*)mask)[(size_t)b * PG + pg] = fm;
}

// ---------------- K3: out = points * mask, flat order, 4 groups/thread ------
// Block covers 16 KiB contiguous of one (b,c) plane; 4 independent mask loads
// issue together, then up to 4 independent pts loads -> deep MLP.
__global__ __launch_bounds__(256) void mul_kernel(const float* __restrict__ pts,
                                                  const float* __restrict__ mask,
                                                  float* __restrict__ out) {
    int gid = blockIdx.x;            // BB * CC * 64 = 21504, linear over tensor
    int seg = gid & 63;              // 16 KiB segment within (b,c) plane
    int t   = gid >> 6;              // b*CC + c
    int b   = t / CC;
    int pg0 = (seg << 10) + threadIdx.x;

    const v4f* mk = (const v4f*)mask + (size_t)b * PG + pg0;
    const v4f* src = (const v4f*)pts + (size_t)t * PG + pg0;
    v4f*       dst = (v4f*)out       + (size_t)t * PG + pg0;

    v4f m0 = mk[0];
    v4f m1 = mk[256];
    v4f m2 = mk[512];
    v4f m3 = mk[768];

    unsigned n0 = __float_as_uint(m0.x) | __float_as_uint(m0.y) | __float_as_uint(m0.z) | __float_as_uint(m0.w);
    unsigned n1 = __float_as_uint(m1.x) | __float_as_uint(m1.y) | __float_as_uint(m1.z) | __float_as_uint(m1.w);
    unsigned n2 = __float_as_uint(m2.x) | __float_as_uint(m2.y) | __float_as_uint(m2.z) | __float_as_uint(m2.w);
    unsigned n3 = __float_as_uint(m3.x) | __float_as_uint(m3.y) | __float_as_uint(m3.z) | __float_as_uint(m3.w);

    v4f z; z.x = 0.f; z.y = 0.f; z.z = 0.f; z.w = 0.f;
    v4f o0 = z, o1 = z, o2 = z, o3 = z;

    if (n0) { v4f v = src[0];   o0.x = v.x * m0.x; o0.y = v.y * m0.y; o0.z = v.z * m0.z; o0.w = v.w * m0.w; }
    if (n1) { v4f v = src[256]; o1.x = v.x * m1.x; o1.y = v.y * m1.y; o1.z = v.z * m1.z; o1.w = v.w * m1.w; }
    if (n2) { v4f v = src[512]; o2.x = v.x * m2.x; o2.y = v.y * m2.y; o2.z = v.z * m2.z; o2.w = v.w * m2.w; }
    if (n3) { v4f v = src[768]; o3.x = v.x * m3.x; o3.y = v.y * m3.y; o3.z = v.z * m3.z; o3.w = v.w * m3.w; }

    dst[0]   = o0;
    dst[256] = o1;
    dst[512] = o2;
    dst[768] = o3;
}

// ---------------- fallback (ws too small): two-kernel path ------------------
__global__ __launch_bounds__(256) void probs_kernel_fb(const float* __restrict__ pts,
                                                       float* __restrict__ probs) {
    int tid = blockIdx.x * blockDim.x + threadIdx.x;
    int pix = tid << 2;
    int b   = pix >> 18;
    int off = pix & (HWSZ - 1);
    const float4* base = (const float4*)(pts + (size_t)b * CC * HWSZ + off);
    float4 m = base[0];
#pragma unroll 4
    for (int c = 1; c < CM; ++c) {
        float4 v = base[c * (HWSZ / 4)];
        m.x = fmaxf(m.x, v.x); m.y = fmaxf(m.y, v.y);
        m.z = fmaxf(m.z, v.z); m.w = fmaxf(m.w, v.w);
    }
    ((float4*)probs)[tid] = m;
}

__global__ __launch_bounds__(256) void nms_mul_kernel_fb(const float* __restrict__ pts,
                                                         const float* __restrict__ probs,
                                                         float* __restrict__ out) {
    int tid = blockIdx.x * blockDim.x + threadIdx.x;
    int pix = tid << 2;
    int b   = pix >> 18;
    int off = pix & (HWSZ - 1);
    int h   = off >> 9;
    int w0  = off & (WW - 1);
    const float* pb = probs + b * HWSZ;
    float rows[3][6];
#pragma unroll
    for (int r = 0; r < 3; ++r) {
        int hh = h + r - 1;
        bool hv = (hh >= 0) & (hh < HH);
        const float* rp = pb + hh * WW;
#pragma unroll
        for (int ci = 0; ci < 6; ++ci) {
            int ww = w0 + ci - 1;
            bool wv = (ww >= 0) & (ww < WW);
            rows[r][ci] = (hv & wv) ? rp[ww] : 0.0f;
        }
    }
    float fm[4];
    bool any = false;
#pragma unroll
    for (int j = 0; j < 4; ++j) {
        float v = rows[1][j + 1];
        bool m = (v >  rows[0][j]) & (v >  rows[0][j + 1]) & (v >  rows[0][j + 2])
               & (v >  rows[1][j]) & (v >= rows[1][j + 2])
               & (v >= rows[2][j]) & (v >= rows[2][j + 1]) & (v >= rows[2][j + 2]);
        fm[j] = m ? 1.0f : 0.0f;
        any |= m;
    }
    size_t bo = (size_t)b * CC * HWSZ + off;
    const float4* src = (const float4*)(pts + bo);
    float4* dst = (float4*)(out + bo);
    if (any) {
#pragma unroll 4
        for (int c = 0; c < CC; ++c) {
            float4 v = src[c * (HWSZ / 4)];
            float4 o;
            o.x = v.x * fm[0]; o.y = v.y * fm[1];
            o.z = v.z * fm[2]; o.w = v.w * fm[3];
            dst[c * (HWSZ / 4)] = o;
        }
    } else {
        float4 z = make_float4(0.f, 0.f, 0.f, 0.f);
#pragma unroll 4
        for (int c = 0; c < CC; ++c) dst[c * (HWSZ / 4)] = z;
    }
}

extern "C" void kernel_launch(void* const* d_in, const int* in_sizes, int n_in,
                              void* d_out, int out_size, void* d_ws, size_t ws_size,
                              hipStream_t stream) {
    const float* pts = (const float*)d_in[0];
    float* out = (float*)d_out;
    float* ws  = (float*)d_ws;

    const size_t MB4 = (size_t)BB * HWSZ * sizeof(float);   // 4 MiB plane
    dim3 blk(256);
    dim3 grd_pg(BB * PG / 256);                              // 1024

    if (ws_size >= (NCH + 1) * MB4) {                        // 20 MiB needed
        float* partial = ws;                                 // 16 MiB
        float* mask    = ws + (size_t)NCH * BB * HWSZ;       // 4 MiB
        partial_max_kernel<<<dim3(BB * NCH * PG / 256), blk, 0, stream>>>(pts, partial);
        fused_mask_kernel<<<grd_pg, blk, 0, stream>>>(partial, mask);
        mul_kernel<<<dim3(BB * CC * 64), blk, 0, stream>>>(pts, mask, out);
    } else {                                                 // 4 MiB fallback
        float* probs = ws;
        probs_kernel_fb<<<grd_pg, blk, 0, stream>>>(pts, probs);
        nms_mul_kernel_fb<<<grd_pg, blk, 0, stream>>>(pts, probs, out);
    }
}